// Round 3
// baseline (726.634 us; speedup 1.0000x reference)
//
#include <hip/hip_runtime.h>
#include <hip/hip_cooperative_groups.h>

namespace cg = cooperative_groups;

#define BB 16
#define NN 2048
#define FF 128
#define NEG 0.01f
#define CH 128         // chunks per batch
#define CL (NN / CH)   // chunk length = 16

// ---------------------------------------------------------------------------
// K1: Wh = h @ W  (fp32, LDS-tiled), fused f1 = Wh·a1, f2 = Wh·a2
// ---------------------------------------------------------------------------
__global__ __launch_bounds__(256) void k_wh(const float* __restrict__ h,
                                            const float* __restrict__ Wg,
                                            const float* __restrict__ a,
                                            float* __restrict__ Wh,
                                            float* __restrict__ f1,
                                            float* __restrict__ f2) {
    __shared__ float Ws[64 * 128];   // [k][f] half-K tile (32 KB)
    __shared__ float hsT[64 * 36];   // [k][row] transposed h tile, pad 36 (9 KB)

    const int tid  = threadIdx.x;
    const int fg   = tid & 31;        // f-group
    const int slot = tid >> 5;        // row-slot 0..7
    const int f4   = fg * 4;
    const int rowBase = blockIdx.x * 32;

    float acc[4][4];
#pragma unroll
    for (int r = 0; r < 4; ++r)
#pragma unroll
        for (int c = 0; c < 4; ++c) acc[r][c] = 0.f;

    const float4* Wg4 = (const float4*)Wg;
    const float4* hg4 = (const float4*)h;

    for (int kh = 0; kh < 128; kh += 64) {
        __syncthreads();
        for (int idx = tid; idx < 64 * 32; idx += 256) {
            int kk = idx >> 5, ff = idx & 31;
            ((float4*)Ws)[kk * 32 + ff] = Wg4[(size_t)(kh + kk) * 32 + ff];
        }
#pragma unroll
        for (int pass = 0; pass < 2; ++pass) {
            int idx = pass * 256 + tid;            // 0..511
            int kq = idx & 15, row = idx >> 4;     // kq 0..15, row 0..31
            float4 h4 = hg4[(size_t)(rowBase + row) * 32 + (kh >> 2) + kq];
            hsT[(kq * 4 + 0) * 36 + row] = h4.x;
            hsT[(kq * 4 + 1) * 36 + row] = h4.y;
            hsT[(kq * 4 + 2) * 36 + row] = h4.z;
            hsT[(kq * 4 + 3) * 36 + row] = h4.w;
        }
        __syncthreads();
#pragma unroll 8
        for (int kk = 0; kk < 64; ++kk) {
            float4 wv = *(const float4*)&Ws[kk * 128 + f4];
            float4 hv = *(const float4*)&hsT[kk * 36 + slot * 4];
            acc[0][0] += hv.x * wv.x; acc[0][1] += hv.x * wv.y; acc[0][2] += hv.x * wv.z; acc[0][3] += hv.x * wv.w;
            acc[1][0] += hv.y * wv.x; acc[1][1] += hv.y * wv.y; acc[1][2] += hv.y * wv.z; acc[1][3] += hv.y * wv.w;
            acc[2][0] += hv.z * wv.x; acc[2][1] += hv.z * wv.y; acc[2][2] += hv.z * wv.z; acc[2][3] += hv.z * wv.w;
            acc[3][0] += hv.w * wv.x; acc[3][1] += hv.w * wv.y; acc[3][2] += hv.w * wv.z; acc[3][3] += hv.w * wv.w;
        }
    }

    const float4* ag4 = (const float4*)a;
    float4 a1v = ag4[fg];
    float4 a2v = ag4[32 + fg];

#pragma unroll
    for (int r = 0; r < 4; ++r) {
        int row = rowBase + slot * 4 + r;
        float4 o; o.x = acc[r][0]; o.y = acc[r][1]; o.z = acc[r][2]; o.w = acc[r][3];
        *(float4*)&Wh[(size_t)row * 128 + f4] = o;
        float p1 = acc[r][0] * a1v.x + acc[r][1] * a1v.y + acc[r][2] * a1v.z + acc[r][3] * a1v.w;
        float p2 = acc[r][0] * a2v.x + acc[r][1] * a2v.y + acc[r][2] * a2v.z + acc[r][3] * a2v.w;
#pragma unroll
        for (int m = 16; m >= 1; m >>= 1) {
            p1 += __shfl_xor(p1, m);
            p2 += __shfl_xor(p2, m);
        }
        if (fg == 0) { f1[row] = p1; f2[row] = p2; }
    }
}

// ---------------------------------------------------------------------------
// wave-level inclusive scan (width 64)
// ---------------------------------------------------------------------------
__device__ __forceinline__ float wave_incl_scan(float s, int lane) {
#pragma unroll
    for (int m = 1; m <= 32; m <<= 1) {
        float o = __shfl_up(s, m);
        if (lane >= m) s += o;
    }
    return s;
}

#define WAVE_SYNC() do { __builtin_amdgcn_wave_barrier(); asm volatile("" ::: "memory"); } while (0)

// ---------------------------------------------------------------------------
// K2: 32 blocks x 1024 threads.
//  task 0 (blocks 0-15): sort f1 asc -> SF1g; shuffle scans -> PAg (exclusive
//    prefix of exp(0.01*sf1), length N+1) and SAg (suffix of exp(sf1), N+1).
//  task 1 (blocks 16-31): sort (f2,idx) pairs -> SKg, PERM; KIDX[i] =
//    #{t : sf2[t] <= -f1[i]}; bin rows by chunk(KIDX) -> ROWS/BOFF.
// ---------------------------------------------------------------------------
__global__ __launch_bounds__(1024) void k_sort2(const float* __restrict__ f1,
                                                const float* __restrict__ f2,
                                                float* __restrict__ SF1g,
                                                float* __restrict__ PAg,
                                                float* __restrict__ SAg,
                                                float* __restrict__ SKg,
                                                int* __restrict__ PERM,
                                                int* __restrict__ KIDX,
                                                int* __restrict__ ROWS,
                                                int* __restrict__ BOFF) {
    __shared__ float sKey[NN];
    __shared__ int   sIdx[NN];
    __shared__ float wtot[16];
    __shared__ int   hist[CH];
    __shared__ int   hscan[CH + 1];
    __shared__ int   sbuf[CH];

    const int tid  = threadIdx.x;
    const int lane = tid & 63;
    const int w    = tid >> 6;
    const int b    = blockIdx.x & 15;
    const int task = blockIdx.x >> 4;

    const float* f1b = f1 + b * NN;
    const float* f2b = f2 + b * NN;

    if (task == 0) {
        for (int i = tid; i < NN; i += 1024) sKey[i] = f1b[i];
    } else {
        for (int i = tid; i < NN; i += 1024) { sKey[i] = f2b[i]; sIdx[i] = i; }
    }

    // ---- bitonic sort ascending; barrier only around cross-wave phases ----
    int prevj = 1024;  // force barrier before first phase (covers initial load)
    for (int k = 2; k <= NN; k <<= 1) {
        for (int j = k >> 1; j > 0; j >>= 1) {
            if (j >= 128 || prevj >= 128) __syncthreads();
            else WAVE_SYNC();
            int mask = j - 1;
            int i   = ((tid & ~mask) << 1) | (tid & mask);
            int ixj = i | j;
            bool up = ((i & k) == 0);
            float av = sKey[i], bv = sKey[ixj];
            if ((av > bv) == up) {
                sKey[i] = bv; sKey[ixj] = av;
                if (task == 1) { int t2 = sIdx[i]; sIdx[i] = sIdx[ixj]; sIdx[ixj] = t2; }
            }
            prevj = j;
        }
    }
    __syncthreads();

    if (task == 0) {
        for (int i = tid; i < NN; i += 1024) SF1g[b * NN + i] = sKey[i];
        const size_t pbase = (size_t)b * (NN + 1);
        // ---- scan 1: exclusive prefix of exp(0.01 * sf1) ----
        {
            float a0 = expf(NEG * sKey[2 * tid]);
            float a1 = expf(NEG * sKey[2 * tid + 1]);
            float s = a0 + a1;
            float v = wave_incl_scan(s, lane);
            if (lane == 63) wtot[w] = v;
            __syncthreads();
            float off = 0.f;
#pragma unroll
            for (int ww = 0; ww < 16; ++ww) off += (ww < w) ? wtot[ww] : 0.f;
            float excl = off + v - s;
            PAg[pbase + 2 * tid]     = excl;
            PAg[pbase + 2 * tid + 1] = excl + a0;
            if (tid == 1023) PAg[pbase + NN] = off + v;
        }
        __syncthreads();   // protect wtot reuse
        // ---- scan 2: suffix sums of exp(sf1) (scan reversed array) ----
        {
            float y0 = expf(sKey[NN - 1 - 2 * tid]);
            float y1 = expf(sKey[NN - 2 - 2 * tid]);
            float s = y0 + y1;
            float v = wave_incl_scan(s, lane);
            if (lane == 63) wtot[w] = v;
            __syncthreads();
            float off = 0.f;
#pragma unroll
            for (int ww = 0; ww < 16; ++ww) off += (ww < w) ? wtot[ww] : 0.f;
            SAg[pbase + NN - 1 - 2 * tid] = off + (v - s) + y0;
            SAg[pbase + NN - 2 - 2 * tid] = off + v;
            if (tid == 0) SAg[pbase + NN] = 0.f;
        }
    } else {
        for (int i = tid; i < NN; i += 1024) {
            SKg[b * NN + i]  = sKey[i];
            PERM[b * NN + i] = sIdx[i];
        }
        if (tid < CH) hist[tid] = 0;
        __syncthreads();
        // KIDX + chunk binning histogram (sIdx reused to stash chunk ids;
        // safe: each thread's PERM writes above precede its sIdx overwrite,
        // partitions are identical/disjoint per thread).
        for (int i = tid; i < NN; i += 1024) {
            float tau = -f1b[i];
            int lo = 0, hi = NN;
            while (lo < hi) { int m = (lo + hi) >> 1; if (sKey[m] <= tau) lo = m + 1; else hi = m; }
            KIDX[b * NN + i] = lo;
            int c = lo / CL;
            if (c > CH - 1) c = CH - 1;   // k == NN -> last chunk (r = CL)
            sIdx[i] = c;
            atomicAdd(&hist[c], 1);
        }
        __syncthreads();
        // ---- exclusive scan of hist (Hillis-Steele over CH=128) ----
        if (tid < CH) sbuf[tid] = hist[tid];
        for (int off = 1; off < CH; off <<= 1) {
            __syncthreads();
            int v = 0;
            if (tid < CH) { v = sbuf[tid]; if (tid >= off) v += sbuf[tid - off]; }
            __syncthreads();
            if (tid < CH) sbuf[tid] = v;
        }
        __syncthreads();
        if (tid == 0) hscan[0] = 0;
        if (tid < CH) hscan[tid + 1] = sbuf[tid];
        __syncthreads();
        if (tid <= CH) BOFF[b * (CH + 1) + tid] = hscan[tid];
        if (tid < CH) hist[tid] = hscan[tid];   // reuse hist as scatter cursor
        __syncthreads();
        for (int i = tid; i < NN; i += 1024) {
            int c = sIdx[i];
            int pos = atomicAdd(&hist[c], 1);
            ROWS[b * NN + pos] = i;
        }
    }
}

// ---------------------------------------------------------------------------
// K3: per-j softmax denominators -> u_j = e^{f2}/D, w_j = e^{0.01 f2}/D
//  8 blocks per batch (t-slices of 256) for CU utilization.
// ---------------------------------------------------------------------------
__global__ __launch_bounds__(256) void k_uw(const float* __restrict__ SF1g,
                                            const float* __restrict__ PAg,
                                            const float* __restrict__ SAg,
                                            const float* __restrict__ SKg,
                                            float* __restrict__ Uarr,
                                            float* __restrict__ Warr) {
    __shared__ float sS[NN];
    __shared__ float sP[NN + 1];
    __shared__ float sA[NN + 1];
    const int b = blockIdx.x >> 3;
    const int q = blockIdx.x & 7;
    const int tid = threadIdx.x;
    const size_t pbase = (size_t)b * (NN + 1);
    for (int i = tid; i < NN; i += 256) sS[i] = SF1g[b * NN + i];
    for (int i = tid; i < NN + 1; i += 256) { sP[i] = PAg[pbase + i]; sA[i] = SAg[pbase + i]; }
    __syncthreads();
    const int t = q * 256 + tid;
    float f2v = SKg[b * NN + t];
    float tau = -f2v;
    int lo = 0, hi = NN;
    while (lo < hi) { int m = (lo + hi) >> 1; if (sS[m] <= tau) lo = m + 1; else hi = m; }
    float eS = expf(NEG * f2v);
    float eF = expf(f2v);
    float inv = 1.0f / (eS * sP[lo] + eF * sA[lo]);
    Uarr[b * NN + t] = eF * inv;
    Warr[b * NN + t] = eS * inv;
}

// ---------------------------------------------------------------------------
// K4 (fused tail, cooperative): one Wh gather total.
//  Phase 1: block (b,c) walks its 16-elem chunk once; LOCAL 128-wide prefix
//           kept in LDS; chunk totals -> CU/CW.          grid.sync()
//  Phase 2: c==0 blocks scan the CH totals in place (exclusive) + TOT.
//                                                        grid.sync()
//  Phase 3: each block adds its global offset to the LDS prefix and emits
//           its bucketed output rows (ROWS/BOFF from k_sort2).
// ---------------------------------------------------------------------------
__global__ __launch_bounds__(128, 4) void k_fused(const float* __restrict__ Wh,
                                                  const float* __restrict__ Uarr,
                                                  const float* __restrict__ Warr,
                                                  const int* __restrict__ PERM,
                                                  float* __restrict__ CU,
                                                  float* __restrict__ CW,
                                                  float* __restrict__ TOT,
                                                  const float* __restrict__ f1,
                                                  const int* __restrict__ KIDX,
                                                  const int* __restrict__ ROWS,
                                                  const int* __restrict__ BOFF,
                                                  float* __restrict__ out) {
    __shared__ float pU[CL + 1][FF];   // 8704 B
    __shared__ float pW[CL + 1][FF];   // 8704 B  (17.4 KB total -> 9 blocks/CU)

    const int blk = blockIdx.x;
    const int b = blk / CH, c = blk % CH;
    const int f = threadIdx.x;

    // ---- phase 1: local prefix + chunk totals ----
    const int base = b * NN + c * CL;
    const float* Whb = Wh + (size_t)b * NN * FF;
    float aU = 0.f, aW = 0.f;
#pragma unroll
    for (int t = 0; t < CL; ++t) {
        pU[t][f] = aU; pW[t][f] = aW;
        int j = PERM[base + t];
        float whv = Whb[(size_t)j * FF + f];
        aU += Uarr[base + t] * whv;
        aW += Warr[base + t] * whv;
    }
    pU[CL][f] = aU; pW[CL][f] = aW;
    CU[(size_t)blk * FF + f] = aU;
    CW[(size_t)blk * FF + f] = aW;

    cg::this_grid().sync();

    // ---- phase 2: exclusive scan of chunk totals (c==0 blocks only) ----
    if (c == 0) {
        float sU = 0.f, sW = 0.f;
#pragma unroll 8
        for (int cc = 0; cc < CH; ++cc) {
            size_t idx = (size_t)(b * CH + cc) * FF + f;
            float tU = CU[idx], tW = CW[idx];
            CU[idx] = sU; CW[idx] = sW;
            sU += tU; sW += tW;
        }
        TOT[b * FF + f] = sU;
    }

    cg::this_grid().sync();

    // ---- phase 3: emit (LDS local prefix + global offset) ----
    const float offU = CU[(size_t)blk * FF + f];
    const float offW = CW[(size_t)blk * FF + f];
    const float totU = TOT[b * FF + f];
    const int rb = BOFF[b * (CH + 1) + c];
    const int re = BOFF[b * (CH + 1) + c + 1];
    for (int idx = rb; idx < re; ++idx) {
        int i = ROWS[b * NN + idx];
        int k = KIDX[b * NN + i];
        int r = k - c * CL;            // 0..CL (CL only for k==NN in last chunk)
        float f1v = f1[b * NN + i];
        float alpha = expf(NEG * f1v);
        float beta  = expf(f1v);
        out[((size_t)(b * NN + i)) * FF + f] =
            alpha * (offW + pW[r][f]) + beta * (totU - (offU + pU[r][f]));
    }
}

// ---------------------------------------------------------------------------
// Fallback tail (used only if cooperative launch is rejected): round-2 path.
// ---------------------------------------------------------------------------
__global__ __launch_bounds__(128) void k_chunk(const float* __restrict__ Wh,
                                               const float* __restrict__ Uarr,
                                               const float* __restrict__ Warr,
                                               const int* __restrict__ PERM,
                                               float* __restrict__ CU,
                                               float* __restrict__ CW) {
    int blk = blockIdx.x;
    int b = blk / CH, c = blk % CH;
    int f = threadIdx.x;
    int base = b * NN + c * CL;
    const float* Whb = Wh + (size_t)b * NN * FF;
    float aU = 0.f, aW = 0.f;
#pragma unroll
    for (int t = 0; t < CL; ++t) {
        int j = PERM[base + t];
        float uv = Uarr[base + t], wv = Warr[base + t];
        float whv = Whb[(size_t)j * FF + f];
        aU += uv * whv; aW += wv * whv;
    }
    CU[(size_t)blk * FF + f] = aU;
    CW[(size_t)blk * FF + f] = aW;
}

__global__ __launch_bounds__(128) void k_offsets(float* __restrict__ CU,
                                                 float* __restrict__ CW,
                                                 float* __restrict__ TOT) {
    int b = blockIdx.x, f = threadIdx.x;
    float aU = 0.f, aW = 0.f;
#pragma unroll 8
    for (int c = 0; c < CH; ++c) {
        size_t idx = (size_t)(b * CH + c) * FF + f;
        float tU = CU[idx], tW = CW[idx];
        CU[idx] = aU; CW[idx] = aW;
        aU += tU; aW += tW;
    }
    TOT[b * FF + f] = aU;
}

__global__ __launch_bounds__(128) void k_emit(const float* __restrict__ Wh,
                                              const float* __restrict__ Uarr,
                                              const float* __restrict__ Warr,
                                              const int* __restrict__ PERM,
                                              const float* __restrict__ CU,
                                              const float* __restrict__ CW,
                                              const float* __restrict__ TOT,
                                              const float* __restrict__ f1,
                                              const int* __restrict__ KIDX,
                                              const int* __restrict__ ROWS,
                                              const int* __restrict__ BOFF,
                                              float* __restrict__ out) {
    __shared__ float pU[CL + 1][FF];
    __shared__ float pW[CL + 1][FF];

    const int blk = blockIdx.x;
    const int b = blk / CH, c = blk % CH;
    const int f = threadIdx.x;

    float aU = CU[(size_t)blk * FF + f];
    float aW = CW[(size_t)blk * FF + f];
    const float totU = TOT[b * FF + f];

    const int base = b * NN + c * CL;
    const float* Whb = Wh + (size_t)b * NN * FF;
#pragma unroll
    for (int t = 0; t < CL; ++t) {
        pU[t][f] = aU; pW[t][f] = aW;
        int j = PERM[base + t];
        float whv = Whb[(size_t)j * FF + f];
        aU += Uarr[base + t] * whv;
        aW += Warr[base + t] * whv;
    }
    pU[CL][f] = aU; pW[CL][f] = aW;
    __syncthreads();

    const int rb = BOFF[b * (CH + 1) + c];
    const int re = BOFF[b * (CH + 1) + c + 1];
    for (int idx = rb; idx < re; ++idx) {
        int i = ROWS[b * NN + idx];
        int k = KIDX[b * NN + i];
        int r = k - c * CL;
        float f1v = f1[b * NN + i];
        float alpha = expf(NEG * f1v);
        float beta  = expf(f1v);
        out[((size_t)(b * NN + i)) * FF + f] = alpha * pW[r][f] + beta * (totU - pU[r][f]);
    }
}

// ---------------------------------------------------------------------------
extern "C" void kernel_launch(void* const* d_in, const int* in_sizes, int n_in,
                              void* d_out, int out_size, void* d_ws, size_t ws_size,
                              hipStream_t stream) {
    const float* h  = (const float*)d_in[0];
    // d_in[1] = adj — unused by the reference; never read.
    const float* W  = (const float*)d_in[2];
    const float* a  = (const float*)d_in[3];
    float* out = (float*)d_out;

    float* ws = (float*)d_ws;
    float* Wh   = ws;  ws += (size_t)BB * NN * FF;         // 4,194,304
    float* f1   = ws;  ws += BB * NN;
    float* f2   = ws;  ws += BB * NN;
    float* SF1  = ws;  ws += BB * NN;
    float* PA   = ws;  ws += BB * (NN + 1);                // 32,784
    float* SA   = ws;  ws += BB * (NN + 1);
    float* SK   = ws;  ws += BB * NN;
    float* Uarr = ws;  ws += BB * NN;
    float* Warr = ws;  ws += BB * NN;
    float* CU   = ws;  ws += (size_t)BB * CH * FF;         // 262,144
    float* CW   = ws;  ws += (size_t)BB * CH * FF;
    float* TOT  = ws;  ws += BB * FF;
    int* PERM = (int*)ws;  ws += BB * NN;
    int* KIDX = (int*)ws;  ws += BB * NN;
    int* ROWS = (int*)ws;  ws += BB * NN;
    int* BOFF = (int*)ws;  // BB*(CH+1) ints

    k_wh    <<<(BB * NN) / 32, 256, 0, stream>>>(h, W, a, Wh, f1, f2);
    k_sort2 <<<2 * BB, 1024, 0, stream>>>(f1, f2, SF1, PA, SA, SK, PERM, KIDX, ROWS, BOFF);
    k_uw    <<<BB * 8, 256, 0, stream>>>(SF1, PA, SA, SK, Uarr, Warr);

    {
        const float* WhC = Wh; const float* UaC = Uarr; const float* WaC = Warr;
        const int* PeC = PERM; const float* f1C = f1; const int* KiC = KIDX;
        const int* RoC = ROWS; const int* BoC = BOFF;
        void* args[] = {(void*)&WhC, (void*)&UaC, (void*)&WaC, (void*)&PeC,
                        (void*)&CU, (void*)&CW, (void*)&TOT, (void*)&f1C,
                        (void*)&KiC, (void*)&RoC, (void*)&BoC, (void*)&out};
        hipError_t cerr = hipLaunchCooperativeKernel(
            reinterpret_cast<const void*>(&k_fused),
            dim3(BB * CH), dim3(128), args, 0, stream);
        if (cerr != hipSuccess) {
            // fallback: round-2 three-kernel tail (correctness-equivalent)
            k_chunk  <<<BB * CH, 128, 0, stream>>>(Wh, Uarr, Warr, PERM, CU, CW);
            k_offsets<<<BB, 128, 0, stream>>>(CU, CW, TOT);
            k_emit   <<<BB * CH, 128, 0, stream>>>(Wh, Uarr, Warr, PERM, CU, CW, TOT,
                                                   f1, KIDX, ROWS, BOFF, out);
        }
    }
}

// Round 4
// 380.872 us; speedup vs baseline: 1.9078x; 1.9078x over previous
//
#include <hip/hip_runtime.h>

#define BB 16
#define NN 2048
#define FF 128
#define NEG 0.01f
#define CH 128         // chunks per batch
#define CL (NN / CH)   // chunk length = 16

// ---------------------------------------------------------------------------
// K1: Wh = h @ W  (fp32, LDS-tiled), fused f1 = Wh·a1, f2 = Wh·a2
// ---------------------------------------------------------------------------
__global__ __launch_bounds__(256) void k_wh(const float* __restrict__ h,
                                            const float* __restrict__ Wg,
                                            const float* __restrict__ a,
                                            float* __restrict__ Wh,
                                            float* __restrict__ f1,
                                            float* __restrict__ f2) {
    __shared__ float Ws[64 * 128];   // [k][f] half-K tile (32 KB)
    __shared__ float hsT[64 * 36];   // [k][row] transposed h tile, pad 36 (9 KB)

    const int tid  = threadIdx.x;
    const int fg   = tid & 31;        // f-group
    const int slot = tid >> 5;        // row-slot 0..7
    const int f4   = fg * 4;
    const int rowBase = blockIdx.x * 32;

    float acc[4][4];
#pragma unroll
    for (int r = 0; r < 4; ++r)
#pragma unroll
        for (int c = 0; c < 4; ++c) acc[r][c] = 0.f;

    const float4* Wg4 = (const float4*)Wg;
    const float4* hg4 = (const float4*)h;

    for (int kh = 0; kh < 128; kh += 64) {
        __syncthreads();
        for (int idx = tid; idx < 64 * 32; idx += 256) {
            int kk = idx >> 5, ff = idx & 31;
            ((float4*)Ws)[kk * 32 + ff] = Wg4[(size_t)(kh + kk) * 32 + ff];
        }
#pragma unroll
        for (int pass = 0; pass < 2; ++pass) {
            int idx = pass * 256 + tid;            // 0..511
            int kq = idx & 15, row = idx >> 4;     // kq 0..15, row 0..31
            float4 h4 = hg4[(size_t)(rowBase + row) * 32 + (kh >> 2) + kq];
            hsT[(kq * 4 + 0) * 36 + row] = h4.x;
            hsT[(kq * 4 + 1) * 36 + row] = h4.y;
            hsT[(kq * 4 + 2) * 36 + row] = h4.z;
            hsT[(kq * 4 + 3) * 36 + row] = h4.w;
        }
        __syncthreads();
#pragma unroll 8
        for (int kk = 0; kk < 64; ++kk) {
            float4 wv = *(const float4*)&Ws[kk * 128 + f4];
            float4 hv = *(const float4*)&hsT[kk * 36 + slot * 4];
            acc[0][0] += hv.x * wv.x; acc[0][1] += hv.x * wv.y; acc[0][2] += hv.x * wv.z; acc[0][3] += hv.x * wv.w;
            acc[1][0] += hv.y * wv.x; acc[1][1] += hv.y * wv.y; acc[1][2] += hv.y * wv.z; acc[1][3] += hv.y * wv.w;
            acc[2][0] += hv.z * wv.x; acc[2][1] += hv.z * wv.y; acc[2][2] += hv.z * wv.z; acc[2][3] += hv.z * wv.w;
            acc[3][0] += hv.w * wv.x; acc[3][1] += hv.w * wv.y; acc[3][2] += hv.w * wv.z; acc[3][3] += hv.w * wv.w;
        }
    }

    const float4* ag4 = (const float4*)a;
    float4 a1v = ag4[fg];
    float4 a2v = ag4[32 + fg];

#pragma unroll
    for (int r = 0; r < 4; ++r) {
        int row = rowBase + slot * 4 + r;
        float4 o; o.x = acc[r][0]; o.y = acc[r][1]; o.z = acc[r][2]; o.w = acc[r][3];
        *(float4*)&Wh[(size_t)row * 128 + f4] = o;
        float p1 = acc[r][0] * a1v.x + acc[r][1] * a1v.y + acc[r][2] * a1v.z + acc[r][3] * a1v.w;
        float p2 = acc[r][0] * a2v.x + acc[r][1] * a2v.y + acc[r][2] * a2v.z + acc[r][3] * a2v.w;
#pragma unroll
        for (int m = 16; m >= 1; m >>= 1) {
            p1 += __shfl_xor(p1, m);
            p2 += __shfl_xor(p2, m);
        }
        if (fg == 0) { f1[row] = p1; f2[row] = p2; }
    }
}

// ---------------------------------------------------------------------------
// wave-level inclusive scan (width 64)
// ---------------------------------------------------------------------------
__device__ __forceinline__ float wave_incl_scan(float s, int lane) {
#pragma unroll
    for (int m = 1; m <= 32; m <<= 1) {
        float o = __shfl_up(s, m);
        if (lane >= m) s += o;
    }
    return s;
}

// ---------------------------------------------------------------------------
// Register-resident bitonic compare-exchange (partner distance j, 2<=j<=64).
// Thread t holds elements 2t (v0) and 2t+1 (v1); partner thread = t ^ (j/2)
// is in the same 64-lane wave. Decision ((vl>vu)==up) is computed identically
// on both partners -> consistent exchange, identical semantics to the LDS
// form `if ((a>b)==up) swap`.
// ---------------------------------------------------------------------------
template<bool WITHIDX>
__device__ __forceinline__ void cex_shfl(float& v0, float& v1, int& i0, int& i1,
                                         int tid, int j, int k) {
    const int  pj    = j >> 1;
    const bool islow = ((tid & pj) == 0);
    const bool up    = (((tid << 1) & k) == 0);
    float o0 = __shfl_xor(v0, pj);
    float o1 = __shfl_xor(v1, pj);
    int oi0 = 0, oi1 = 0;
    if (WITHIDX) { oi0 = __shfl_xor(i0, pj); oi1 = __shfl_xor(i1, pj); }
    {
        float vl = islow ? v0 : o0, vu = islow ? o0 : v0;
        if ((vl > vu) == up) { v0 = o0; if (WITHIDX) i0 = oi0; }
    }
    {
        float vl = islow ? v1 : o1, vu = islow ? o1 : v1;
        if ((vl > vu) == up) { v1 = o1; if (WITHIDX) i1 = oi1; }
    }
}

template<bool WITHIDX>
__device__ __forceinline__ void cex_intra(float& v0, float& v1, int& i0, int& i1,
                                          int tid, int k) {
    const bool up = (((tid << 1) & k) == 0);
    if ((v0 > v1) == up) {
        float tv = v0; v0 = v1; v1 = tv;
        if (WITHIDX) { int ti = i0; i0 = i1; i1 = ti; }
    }
}

// Full bitonic sort of 2048 elements, 1024 threads. Phases with j<=64 run in
// registers (shuffle exchange); only j>=128 phases touch LDS. Leaves the
// sorted keys (and idx if WITHIDX) in sKey/sIdx; caller must __syncthreads().
template<bool WITHIDX>
__device__ __forceinline__ void bitonic2048(float* sKey, int* sIdx,
                                            float v0, float v1, int i0, int i1,
                                            int tid) {
    // ---- phase A: k = 2..128 fully register-resident ----
#pragma unroll
    for (int k = 2; k <= 128; k <<= 1) {
#pragma unroll
        for (int j = 64; j >= 2; j >>= 1)
            if (j <= (k >> 1)) cex_shfl<WITHIDX>(v0, v1, i0, i1, tid, j, k);
        cex_intra<WITHIDX>(v0, v1, i0, i1, tid, k);
    }
    sKey[2 * tid] = v0; sKey[2 * tid + 1] = v1;
    if (WITHIDX) { sIdx[2 * tid] = i0; sIdx[2 * tid + 1] = i1; }

    // ---- phase B: k = 256..2048; LDS for j>=128, registers for j<=64 ----
    for (int k = 256; k <= NN; k <<= 1) {
        for (int j = k >> 1; j >= 128; j >>= 1) {
            __syncthreads();
            int mask = j - 1;
            int i   = ((tid & ~mask) << 1) | (tid & mask);
            int ixj = i | j;
            bool up = ((i & k) == 0);
            float av = sKey[i], bv = sKey[ixj];
            if ((av > bv) == up) {
                sKey[i] = bv; sKey[ixj] = av;
                if (WITHIDX) { int t2 = sIdx[i]; sIdx[i] = sIdx[ixj]; sIdx[ixj] = t2; }
            }
        }
        __syncthreads();
        v0 = sKey[2 * tid]; v1 = sKey[2 * tid + 1];
        if (WITHIDX) { i0 = sIdx[2 * tid]; i1 = sIdx[2 * tid + 1]; }
#pragma unroll
        for (int j = 64; j >= 2; j >>= 1) cex_shfl<WITHIDX>(v0, v1, i0, i1, tid, j, k);
        cex_intra<WITHIDX>(v0, v1, i0, i1, tid, k);
        sKey[2 * tid] = v0; sKey[2 * tid + 1] = v1;
        if (WITHIDX) { sIdx[2 * tid] = i0; sIdx[2 * tid + 1] = i1; }
    }
}

// ---------------------------------------------------------------------------
// K2: 32 blocks x 1024 threads.
//  task 0 (blocks 0-15): sort f1 asc -> SF1g; shuffle scans -> PAg (exclusive
//    prefix of exp(0.01*sf1), length N+1) and SAg (suffix of exp(sf1), N+1).
//  task 1 (blocks 16-31): sort (f2,idx) pairs -> SKg, PERM; KIDX[i] =
//    #{t : sf2[t] <= -f1[i]}; bin rows by chunk(KIDX) -> ROWS/BOFF.
// ---------------------------------------------------------------------------
__global__ __launch_bounds__(1024) void k_sort2(const float* __restrict__ f1,
                                                const float* __restrict__ f2,
                                                float* __restrict__ SF1g,
                                                float* __restrict__ PAg,
                                                float* __restrict__ SAg,
                                                float* __restrict__ SKg,
                                                int* __restrict__ PERM,
                                                int* __restrict__ KIDX,
                                                int* __restrict__ ROWS,
                                                int* __restrict__ BOFF) {
    __shared__ float sKey[NN];
    __shared__ int   sIdx[NN];
    __shared__ float wtot[16];
    __shared__ int   hist[CH];
    __shared__ int   hscan[CH + 1];
    __shared__ int   sbuf[CH];

    const int tid  = threadIdx.x;
    const int lane = tid & 63;
    const int w    = tid >> 6;
    const int b    = blockIdx.x & 15;
    const int task = blockIdx.x >> 4;

    const float* f1b = f1 + b * NN;
    const float* f2b = f2 + b * NN;

    if (task == 0) {
        float2 p = ((const float2*)f1b)[tid];
        int i0 = 0, i1 = 0;
        bitonic2048<false>(sKey, sIdx, p.x, p.y, i0, i1, tid);
    } else {
        float2 p = ((const float2*)f2b)[tid];
        bitonic2048<true>(sKey, sIdx, p.x, p.y, 2 * tid, 2 * tid + 1, tid);
    }
    __syncthreads();

    if (task == 0) {
        for (int i = tid; i < NN; i += 1024) SF1g[b * NN + i] = sKey[i];
        const size_t pbase = (size_t)b * (NN + 1);
        // ---- scan 1: exclusive prefix of exp(0.01 * sf1) ----
        {
            float a0 = expf(NEG * sKey[2 * tid]);
            float a1 = expf(NEG * sKey[2 * tid + 1]);
            float s = a0 + a1;
            float v = wave_incl_scan(s, lane);
            if (lane == 63) wtot[w] = v;
            __syncthreads();
            float off = 0.f;
#pragma unroll
            for (int ww = 0; ww < 16; ++ww) off += (ww < w) ? wtot[ww] : 0.f;
            float excl = off + v - s;
            PAg[pbase + 2 * tid]     = excl;
            PAg[pbase + 2 * tid + 1] = excl + a0;
            if (tid == 1023) PAg[pbase + NN] = off + v;
        }
        __syncthreads();   // protect wtot reuse
        // ---- scan 2: suffix sums of exp(sf1) (scan reversed array) ----
        {
            float y0 = expf(sKey[NN - 1 - 2 * tid]);
            float y1 = expf(sKey[NN - 2 - 2 * tid]);
            float s = y0 + y1;
            float v = wave_incl_scan(s, lane);
            if (lane == 63) wtot[w] = v;
            __syncthreads();
            float off = 0.f;
#pragma unroll
            for (int ww = 0; ww < 16; ++ww) off += (ww < w) ? wtot[ww] : 0.f;
            SAg[pbase + NN - 1 - 2 * tid] = off + (v - s) + y0;
            SAg[pbase + NN - 2 - 2 * tid] = off + v;
            if (tid == 0) SAg[pbase + NN] = 0.f;
        }
    } else {
        for (int i = tid; i < NN; i += 1024) {
            SKg[b * NN + i]  = sKey[i];
            PERM[b * NN + i] = sIdx[i];
        }
        if (tid < CH) hist[tid] = 0;
        __syncthreads();
        // KIDX + chunk binning histogram (sIdx reused to stash chunk ids;
        // safe: each thread's PERM writes above precede its sIdx overwrite,
        // partitions are identical/disjoint per thread).
        for (int i = tid; i < NN; i += 1024) {
            float tau = -f1b[i];
            int lo = 0, hi = NN;
            while (lo < hi) { int m = (lo + hi) >> 1; if (sKey[m] <= tau) lo = m + 1; else hi = m; }
            KIDX[b * NN + i] = lo;
            int c = lo / CL;
            if (c > CH - 1) c = CH - 1;   // k == NN -> last chunk (r = CL)
            sIdx[i] = c;
            atomicAdd(&hist[c], 1);
        }
        __syncthreads();
        // ---- exclusive scan of hist (Hillis-Steele over CH=128) ----
        if (tid < CH) sbuf[tid] = hist[tid];
        for (int off = 1; off < CH; off <<= 1) {
            __syncthreads();
            int v = 0;
            if (tid < CH) { v = sbuf[tid]; if (tid >= off) v += sbuf[tid - off]; }
            __syncthreads();
            if (tid < CH) sbuf[tid] = v;
        }
        __syncthreads();
        if (tid == 0) hscan[0] = 0;
        if (tid < CH) hscan[tid + 1] = sbuf[tid];
        __syncthreads();
        if (tid <= CH) BOFF[b * (CH + 1) + tid] = hscan[tid];
        if (tid < CH) hist[tid] = hscan[tid];   // reuse hist as scatter cursor
        __syncthreads();
        for (int i = tid; i < NN; i += 1024) {
            int c = sIdx[i];
            int pos = atomicAdd(&hist[c], 1);
            ROWS[b * NN + pos] = i;
        }
    }
}

// ---------------------------------------------------------------------------
// K3: per-j softmax denominators -> u_j = e^{f2}/D, w_j = e^{0.01 f2}/D
//  8 blocks per batch (t-slices of 256) for CU utilization.
// ---------------------------------------------------------------------------
__global__ __launch_bounds__(256) void k_uw(const float* __restrict__ SF1g,
                                            const float* __restrict__ PAg,
                                            const float* __restrict__ SAg,
                                            const float* __restrict__ SKg,
                                            float* __restrict__ Uarr,
                                            float* __restrict__ Warr) {
    __shared__ float sS[NN];
    __shared__ float sP[NN + 1];
    __shared__ float sA[NN + 1];
    const int b = blockIdx.x >> 3;
    const int q = blockIdx.x & 7;
    const int tid = threadIdx.x;
    const size_t pbase = (size_t)b * (NN + 1);
    for (int i = tid; i < NN; i += 256) sS[i] = SF1g[b * NN + i];
    for (int i = tid; i < NN + 1; i += 256) { sP[i] = PAg[pbase + i]; sA[i] = SAg[pbase + i]; }
    __syncthreads();
    const int t = q * 256 + tid;
    float f2v = SKg[b * NN + t];
    float tau = -f2v;
    int lo = 0, hi = NN;
    while (lo < hi) { int m = (lo + hi) >> 1; if (sS[m] <= tau) lo = m + 1; else hi = m; }
    float eS = expf(NEG * f2v);
    float eF = expf(f2v);
    float inv = 1.0f / (eS * sP[lo] + eF * sA[lo]);
    Uarr[b * NN + t] = eF * inv;
    Warr[b * NN + t] = eS * inv;
}

// ---------------------------------------------------------------------------
// K4: chunk totals (CL=16 walk per block; CH=128 chunks/batch)
// ---------------------------------------------------------------------------
__global__ __launch_bounds__(128) void k_chunk(const float* __restrict__ Wh,
                                               const float* __restrict__ Uarr,
                                               const float* __restrict__ Warr,
                                               const int* __restrict__ PERM,
                                               float* __restrict__ CU,
                                               float* __restrict__ CW) {
    int blk = blockIdx.x;               // b*CH + c
    int b = blk / CH, c = blk % CH;
    int f = threadIdx.x;
    int base = b * NN + c * CL;
    const float* Whb = Wh + (size_t)b * NN * FF;
    float aU = 0.f, aW = 0.f;
#pragma unroll
    for (int t = 0; t < CL; ++t) {
        int j = PERM[base + t];
        float uv = Uarr[base + t], wv = Warr[base + t];
        float whv = Whb[(size_t)j * FF + f];
        aU += uv * whv; aW += wv * whv;
    }
    CU[(size_t)blk * FF + f] = aU;
    CW[(size_t)blk * FF + f] = aW;
}

// ---------------------------------------------------------------------------
// K5: in-place exclusive scan of chunk totals per (b,f); batch total -> TOT.
// ---------------------------------------------------------------------------
__global__ __launch_bounds__(128) void k_offsets(float* __restrict__ CU,
                                                 float* __restrict__ CW,
                                                 float* __restrict__ TOT) {
    int b = blockIdx.x, f = threadIdx.x;
    float aU = 0.f, aW = 0.f;
#pragma unroll 8
    for (int c = 0; c < CH; ++c) {
        size_t idx = (size_t)(b * CH + c) * FF + f;
        float tU = CU[idx], tW = CW[idx];
        CU[idx] = aU; CW[idx] = aW;
        aU += tU; aW += tW;
    }
    TOT[b * FF + f] = aU;   // total of U-weighted sum (only U total needed)
}

// ---------------------------------------------------------------------------
// K6: per-chunk LDS prefix + direct output emission.
// ---------------------------------------------------------------------------
__global__ __launch_bounds__(128) void k_emit(const float* __restrict__ Wh,
                                              const float* __restrict__ Uarr,
                                              const float* __restrict__ Warr,
                                              const int* __restrict__ PERM,
                                              const float* __restrict__ CU,
                                              const float* __restrict__ CW,
                                              const float* __restrict__ TOT,
                                              const float* __restrict__ f1,
                                              const int* __restrict__ KIDX,
                                              const int* __restrict__ ROWS,
                                              const int* __restrict__ BOFF,
                                              float* __restrict__ out) {
    __shared__ float pU[CL + 1][FF];   // 17*128*4 = 8704 B
    __shared__ float pW[CL + 1][FF];

    const int blk = blockIdx.x;
    const int b = blk / CH, c = blk % CH;
    const int f = threadIdx.x;

    float aU = CU[(size_t)blk * FF + f];
    float aW = CW[(size_t)blk * FF + f];
    const float totU = TOT[b * FF + f];

    const int base = b * NN + c * CL;
    const float* Whb = Wh + (size_t)b * NN * FF;
#pragma unroll
    for (int t = 0; t < CL; ++t) {
        pU[t][f] = aU; pW[t][f] = aW;
        int j = PERM[base + t];
        float whv = Whb[(size_t)j * FF + f];
        aU += Uarr[base + t] * whv;
        aW += Warr[base + t] * whv;
    }
    pU[CL][f] = aU; pW[CL][f] = aW;
    __syncthreads();

    const int rb = BOFF[b * (CH + 1) + c];
    const int re = BOFF[b * (CH + 1) + c + 1];
    for (int idx = rb; idx < re; ++idx) {
        int i = ROWS[b * NN + idx];
        int k = KIDX[b * NN + i];
        int r = k - c * CL;            // 0..CL (CL only for k==NN in last chunk)
        float f1v = f1[b * NN + i];
        float alpha = expf(NEG * f1v);
        float beta  = expf(f1v);
        out[((size_t)(b * NN + i)) * FF + f] = alpha * pW[r][f] + beta * (totU - pU[r][f]);
    }
}

// ---------------------------------------------------------------------------
extern "C" void kernel_launch(void* const* d_in, const int* in_sizes, int n_in,
                              void* d_out, int out_size, void* d_ws, size_t ws_size,
                              hipStream_t stream) {
    const float* h  = (const float*)d_in[0];
    // d_in[1] = adj — unused by the reference; never read.
    const float* W  = (const float*)d_in[2];
    const float* a  = (const float*)d_in[3];
    float* out = (float*)d_out;

    float* ws = (float*)d_ws;
    float* Wh   = ws;  ws += (size_t)BB * NN * FF;         // 4,194,304
    float* f1   = ws;  ws += BB * NN;
    float* f2   = ws;  ws += BB * NN;
    float* SF1  = ws;  ws += BB * NN;
    float* PA   = ws;  ws += BB * (NN + 1);                // 32,784
    float* SA   = ws;  ws += BB * (NN + 1);
    float* SK   = ws;  ws += BB * NN;
    float* Uarr = ws;  ws += BB * NN;
    float* Warr = ws;  ws += BB * NN;
    float* CU   = ws;  ws += (size_t)BB * CH * FF;         // 262,144
    float* CW   = ws;  ws += (size_t)BB * CH * FF;
    float* TOT  = ws;  ws += BB * FF;
    int* PERM = (int*)ws;  ws += BB * NN;
    int* KIDX = (int*)ws;  ws += BB * NN;
    int* ROWS = (int*)ws;  ws += BB * NN;
    int* BOFF = (int*)ws;  // BB*(CH+1) ints

    k_wh     <<<(BB * NN) / 32, 256, 0, stream>>>(h, W, a, Wh, f1, f2);
    k_sort2  <<<2 * BB, 1024, 0, stream>>>(f1, f2, SF1, PA, SA, SK, PERM, KIDX, ROWS, BOFF);
    k_uw     <<<BB * 8, 256, 0, stream>>>(SF1, PA, SA, SK, Uarr, Warr);
    k_chunk  <<<BB * CH, 128, 0, stream>>>(Wh, Uarr, Warr, PERM, CU, CW);
    k_offsets<<<BB, 128, 0, stream>>>(CU, CW, TOT);
    k_emit   <<<BB * CH, 128, 0, stream>>>(Wh, Uarr, Warr, PERM, CU, CW, TOT, f1, KIDX, ROWS, BOFF, out);
}